// Round 13
// baseline (706.692 us; speedup 1.0000x reference)
//
#include <hip/hip_runtime.h>
#include <hip/hip_bf16.h>
#include <math.h>

#define TEMP 0.1
#define NC 10   // rerank candidates (true top-8 ⊂ fp16-score top-10; R9 margin model)

typedef float f4 __attribute__((ext_vector_type(4)));
typedef short s8v __attribute__((ext_vector_type(8)));
typedef int   i4v __attribute__((ext_vector_type(4)));
typedef _Float16 h8v __attribute__((ext_vector_type(8)));

__device__ inline short f2bf(float f) {
    __hip_bfloat16 h = __float2bfloat16(f);
    return *reinterpret_cast<short*>(&h);
}

// 16B global->LDS DMA: per-lane global addr, wave-uniform LDS base (+lane*16 by HW).
__device__ __forceinline__ void g2l16(const void* g, void* l) {
    __builtin_amdgcn_global_load_lds(
        (const __attribute__((address_space(1))) void*)g,
        (__attribute__((address_space(3))) void*)l, 16, 0, 0);
}

// ---------- W setup, fused: y=0 quant Wq, y=1 quant Wk, y=2 bf16-cast Wv ----------
__global__ __launch_bounds__(256) void prep_w(
    const float* __restrict__ Wq, const float* __restrict__ Wk,
    const float* __restrict__ Wv,
    signed char* __restrict__ Wql, signed char* __restrict__ Wkl,
    double* __restrict__ wqsc, double* __restrict__ wksc,
    short* __restrict__ Wvh)
{
    const int row = blockIdx.x, tid = threadIdx.x;
    const int which = blockIdx.y;
    if (which == 2) {
        const float4 v = ((const float4*)(Wv + (size_t)row * 1024))[tid];
        __align__(8) short h[4] = {f2bf(v.x), f2bf(v.y), f2bf(v.z), f2bf(v.w)};
        *(short4*)&Wvh[(size_t)row * 1024 + tid * 4] = *(short4*)h;
        return;
    }
    const float* src = which ? Wk : Wq;
    signed char* limbs = which ? Wkl : Wql;
    double* scale = which ? wksc : wqsc;
    const long plane_stride = 1024L * 1024;

    const float4 v = ((const float4*)(src + (size_t)row * 1024))[tid];
    float m = fmaxf(fmaxf(fabsf(v.x), fabsf(v.y)), fmaxf(fabsf(v.z), fabsf(v.w)));
#pragma unroll
    for (int off = 32; off > 0; off >>= 1) m = fmaxf(m, __shfl_down(m, off));
    __shared__ float wmax[4];
    __shared__ int ssig;
    if ((tid & 63) == 0) wmax[tid >> 6] = m;
    __syncthreads();
    if (tid == 0) {
        float rm = fmaxf(fmaxf(wmax[0], wmax[1]), fmaxf(wmax[2], wmax[3]));
        int sig = (rm > 0.f) ? (29 - ilogbf(rm)) : 0;
        ssig = sig;
        scale[row] = ldexp(1.0, -sig);
    }
    __syncthreads();
    const double s2 = ldexp(1.0, ssig);
    float xs[4] = {v.x, v.y, v.z, v.w};
    signed char out[4][4];
#pragma unroll
    for (int e = 0; e < 4; ++e) {
        long X = __double2ll_rn((double)xs[e] * s2);
#pragma unroll
        for (int l = 0; l < 3; ++l) {
            int d = (int)(((X + 128) & 255) - 128);
            out[l][e] = (signed char)d;
            X = (X - d) >> 8;
        }
        out[3][e] = (signed char)X;
    }
#pragma unroll
    for (int l = 0; l < 4; ++l)
        *(char4*)&limbs[(size_t)l * plane_stride + (size_t)row * 1024 + tid * 4] =
            *(char4*)&out[l][0];
}

// ================= device bodies (shared between fused / standalone kernels) ======

struct PrepSm { float wmax[4]; int ssig; };

__device__ __forceinline__ void prepx_body(
    PrepSm* sm, int row, int tid,
    const float* __restrict__ src, signed char* __restrict__ limbs,
    long plane_stride, double* __restrict__ scale, short* __restrict__ hi)
{
    const float4 v = ((const float4*)(src + (size_t)row * 1024))[tid];
    float m = fmaxf(fmaxf(fabsf(v.x), fabsf(v.y)), fmaxf(fabsf(v.z), fabsf(v.w)));
#pragma unroll
    for (int off = 32; off > 0; off >>= 1) m = fmaxf(m, __shfl_down(m, off));
    if ((tid & 63) == 0) sm->wmax[tid >> 6] = m;
    __syncthreads();
    if (tid == 0) {
        float rm = fmaxf(fmaxf(sm->wmax[0], sm->wmax[1]), fmaxf(sm->wmax[2], sm->wmax[3]));
        int sig = (rm > 0.f) ? (29 - ilogbf(rm)) : 0;
        sm->ssig = sig;
        scale[row] = ldexp(1.0, -sig);
    }
    __syncthreads();
    const double s2 = ldexp(1.0, sm->ssig);
    float xs[4] = {v.x, v.y, v.z, v.w};
    signed char out[4][4];
    __align__(8) short h[4];
#pragma unroll
    for (int e = 0; e < 4; ++e) {
        long X = __double2ll_rn((double)xs[e] * s2);
#pragma unroll
        for (int lmb = 0; lmb < 3; ++lmb) {
            int d = (int)(((X + 128) & 255) - 128);
            out[lmb][e] = (signed char)d;
            X = (X - d) >> 8;
        }
        out[3][e] = (signed char)X;
        h[e] = f2bf(xs[e]);
    }
#pragma unroll
    for (int lmb = 0; lmb < 4; ++lmb)
        *(char4*)&limbs[(size_t)lmb * plane_stride + (size_t)row * 1024 + tid * 4] =
            *(char4*)&out[lmb][0];
    *(short4*)&hi[(size_t)row * 1024 + tid * 4] = *(short4*)h;
}

// i8-MFMA fused Q+K projection body (R12-verified; flat LDS pointers).
__device__ __forceinline__ void i8qk_body(
    signed char* As, signed char* Bq, signed char* Bk,
    int xt, int yt, int tid,
    const signed char* __restrict__ Xl,
    const signed char* __restrict__ Wql,
    const signed char* __restrict__ Wkl,
    const double* __restrict__ xsc,
    const double* __restrict__ wqsc, const double* __restrict__ wksc,
    const float* __restrict__ bqb, const float* __restrict__ bkb,
    float* __restrict__ Qf, float* __restrict__ Kf)
{
    const int K = 1024, N = 1024;
    const long MK = 2048L * 1024, NK = 1024L * 1024;

    const int lane = tid & 63, wave = tid >> 6;
    const int wm = wave >> 1, wn = wave & 1;
    const int quad = lane >> 4, l16 = lane & 15;
    const int m0 = yt * 64, n0 = xt * 64;

    const int srow = tid >> 2;
    const int cswz = ((tid & 3) ^ ((srow >> 1) & 3));
    const signed char* ap  = Xl  + (size_t)(m0 + srow) * K + cswz * 16;
    const signed char* bqp = Wql + (size_t)(n0 + srow) * K + cswz * 16;
    const signed char* bkp = Wkl + (size_t)(n0 + srow) * K + cswz * 16;

    signed char* aw  = As + (wave << 10);
    signed char* bqw = Bq + (wave << 10);
    signed char* bkw = Bk + (wave << 10);

    i4v accq[4][2][2] = {};   // level s = i+j-3
    i4v acck[4][2][2] = {};

    const int R0  = wm * 32 + l16;
    const int R1  = wm * 32 + 16 + l16;
    const int c0  = (quad ^ ((R0 >> 1) & 3)) * 16;
    const int c1  = (quad ^ ((R1 >> 1) & 3)) * 16;
    const int Rn0 = wn * 32 + l16;
    const int Rn1 = wn * 32 + 16 + l16;
    const int cn0 = (quad ^ ((Rn0 >> 1) & 3)) * 16;
    const int cn1 = (quad ^ ((Rn1 >> 1) & 3)) * 16;

    for (int k0 = 0; k0 < K; k0 += 64) {
        __syncthreads();
#pragma unroll
        for (int l = 0; l < 4; ++l) {
            g2l16(ap  + l * MK + k0, aw  + l * 4096);
            g2l16(bqp + l * NK + k0, bqw + l * 4096);
            g2l16(bkp + l * NK + k0, bkw + l * 4096);
        }
        __syncthreads();

        i4v aF0[4], aF1[4];
#pragma unroll
        for (int i = 0; i < 4; ++i) {
            aF0[i] = *(const i4v*)(As + i * 4096 + R0 * 64 + c0);
            aF1[i] = *(const i4v*)(As + i * 4096 + R1 * 64 + c1);
        }

#pragma unroll
        for (int j = 0; j < 4; ++j) {
            i4v bq0 = *(const i4v*)(Bq + j * 4096 + Rn0 * 64 + cn0);
            i4v bq1 = *(const i4v*)(Bq + j * 4096 + Rn1 * 64 + cn1);
            i4v bk0 = *(const i4v*)(Bk + j * 4096 + Rn0 * 64 + cn0);
            i4v bk1 = *(const i4v*)(Bk + j * 4096 + Rn1 * 64 + cn1);
#pragma unroll
            for (int i = 0; i < 4; ++i) {
                if (i + j < 3) continue;
                const int s = i + j - 3;
                accq[s][0][0] = __builtin_amdgcn_mfma_i32_16x16x64_i8(aF0[i], bq0, accq[s][0][0], 0, 0, 0);
                accq[s][0][1] = __builtin_amdgcn_mfma_i32_16x16x64_i8(aF0[i], bq1, accq[s][0][1], 0, 0, 0);
                accq[s][1][0] = __builtin_amdgcn_mfma_i32_16x16x64_i8(aF1[i], bq0, accq[s][1][0], 0, 0, 0);
                accq[s][1][1] = __builtin_amdgcn_mfma_i32_16x16x64_i8(aF1[i], bq1, accq[s][1][1], 0, 0, 0);
                acck[s][0][0] = __builtin_amdgcn_mfma_i32_16x16x64_i8(aF0[i], bk0, acck[s][0][0], 0, 0, 0);
                acck[s][0][1] = __builtin_amdgcn_mfma_i32_16x16x64_i8(aF0[i], bk1, acck[s][0][1], 0, 0, 0);
                acck[s][1][0] = __builtin_amdgcn_mfma_i32_16x16x64_i8(aF1[i], bk0, acck[s][1][0], 0, 0, 0);
                acck[s][1][1] = __builtin_amdgcn_mfma_i32_16x16x64_i8(aF1[i], bk1, acck[s][1][1], 0, 0, 0);
            }
        }
    }

    const double wt0 = ldexp(1.0, 24), wt1 = ldexp(1.0, 32);
    const double wt2 = ldexp(1.0, 40), wt3 = ldexp(1.0, 48);
#pragma unroll
    for (int mt = 0; mt < 2; ++mt)
#pragma unroll
        for (int nt = 0; nt < 2; ++nt)
#pragma unroll
            for (int r = 0; r < 4; ++r) {
                int row = m0 + wm * 32 + mt * 16 + quad * 4 + r;
                int col = n0 + wn * 32 + nt * 16 + l16;
                const double xr = xsc[row];
                double dq = wt0 * (double)accq[0][mt][nt][r]
                          + wt1 * (double)accq[1][mt][nt][r]
                          + wt2 * (double)accq[2][mt][nt][r]
                          + wt3 * (double)accq[3][mt][nt][r];
                Qf[(size_t)row * N + col] =
                    (float)(dq * xr * wqsc[col] + (double)bqb[col]);
                double dk = wt0 * (double)acck[0][mt][nt][r]
                          + wt1 * (double)acck[1][mt][nt][r]
                          + wt2 * (double)acck[2][mt][nt][r]
                          + wt3 * (double)acck[3][mt][nt][r];
                Kf[(size_t)row * N + col] =
                    (float)(dk * xr * wksc[col] + (double)bkb[col]);
            }
}

// V projection body, pure bf16 single-MFMA (R8/R12-verified; flat LDS).
__device__ __forceinline__ void v64_body(
    char* Ahc, char* Bhc, int xt, int yt, int tid,
    const short* __restrict__ Ahp, const short* __restrict__ Bhp,
    const float* __restrict__ bias, float* __restrict__ C)
{
    const int K = 1024, N = 1024;
    const int lane = tid & 63, wave = tid >> 6;
    const int wm = wave >> 1, wn = wave & 1;
    const int quad = lane >> 4, l16 = lane & 15;
    const int m0 = yt * 64, n0 = xt * 64;
    const int srow = tid >> 2;
    const int cswz = ((tid & 3) ^ ((srow >> 1) & 3));
    const char* ap = (const char*)(Ahp + (size_t)(m0 + srow) * K) + cswz * 16;
    const char* bp = (const char*)(Bhp + (size_t)(n0 + srow) * K) + cswz * 16;
    char* aw = Ahc + (wave << 10);
    char* bw = Bhc + (wave << 10);

    f4 acc[2][2] = {};
    for (int k0 = 0; k0 < K; k0 += 32) {
        __syncthreads();
        g2l16(ap + 2 * k0, aw);
        g2l16(bp + 2 * k0, bw);
        __syncthreads();

        s8v af[2], bf[2];
#pragma unroll
        for (int t = 0; t < 2; ++t) {
            const int Ra = wm * 32 + t * 16 + l16;
            const int Rb = wn * 32 + t * 16 + l16;
            af[t] = *(const s8v*)(Ahc + Ra * 64 + ((quad ^ ((Ra >> 1) & 3)) << 4));
            bf[t] = *(const s8v*)(Bhc + Rb * 64 + ((quad ^ ((Rb >> 1) & 3)) << 4));
        }
#pragma unroll
        for (int mt = 0; mt < 2; ++mt)
#pragma unroll
            for (int nt = 0; nt < 2; ++nt)
                acc[mt][nt] = __builtin_amdgcn_mfma_f32_16x16x32_bf16(
                    af[mt], bf[nt], acc[mt][nt], 0, 0, 0);
    }
#pragma unroll
    for (int mt = 0; mt < 2; ++mt)
#pragma unroll
        for (int nt = 0; nt < 2; ++nt)
#pragma unroll
            for (int r = 0; r < 4; ++r) {
                int row = m0 + wm * 32 + mt * 16 + quad * 4 + r;
                int col = n0 + wn * 32 + nt * 16 + l16;
                C[(size_t)row * N + col] = acc[mt][nt][r] + bias[col];
            }
}

struct TopkSm {
    float  qrow[1024];
    float  cval[4 * NC];
    int    cidx[4 * NC];
    int    sel[NC];
    double cscore[NC];
    int    topi_s[8];
    float  wts[8];
};

__device__ __forceinline__ void topk_body(
    TopkSm* sm, int p, int tid,
    const float* __restrict__ S,
    const float* __restrict__ Qf,
    const float* __restrict__ Kf,
    const float* __restrict__ Vf,
    float* __restrict__ routes_out,
    float* __restrict__ weights_out,
    float* __restrict__ feat_out,
    int batch)
{
    const int P = 2048, D = 1024;
    const int lane = tid & 63, wave = tid >> 6;

    const float4* sr4 = (const float4*)(S + (size_t)p * P);
    const float4 s0 = sr4[tid];
    const float4 s1 = sr4[tid + 256];
    ((float4*)sm->qrow)[tid] = ((const float4*)(Qf + (size_t)p * D))[tid];

    float v[8] = {s0.x, s0.y, s0.z, s0.w, s1.x, s1.y, s1.z, s1.w};
    int   ji[8];
#pragma unroll
    for (int e = 0; e < 8; ++e) {
        ji[e] = (e < 4) ? (4 * tid + e) : (1024 + 4 * tid + (e - 4));
        if (ji[e] == p) v[e] = -1e30f;   // diagonal mask
    }

    float lv = v[0]; int li = ji[0];
#pragma unroll
    for (int e = 1; e < 8; ++e)
        if (v[e] > lv) { lv = v[e]; li = ji[e]; }

    // per-wave top-NC register tournament (no barriers)
    float cv_ = -INFINITY; int ci_ = 0x7fffffff;
#pragma unroll 1
    for (int it = 0; it < NC; ++it) {
        float bv = lv; int bi = li;
#pragma unroll
        for (int off = 32; off > 0; off >>= 1) {
            float ov = __shfl_xor(bv, off);
            int   oi = __shfl_xor(bi, off);
            if (ov > bv || (ov == bv && oi < bi)) { bv = ov; bi = oi; }
        }
        if (lane == it) { cv_ = bv; ci_ = bi; }
#pragma unroll
        for (int e = 0; e < 8; ++e)
            if (ji[e] == bi) v[e] = -INFINITY;
        lv = v[0]; li = ji[0];
#pragma unroll
        for (int e = 1; e < 8; ++e)
            if (v[e] > lv) { lv = v[e]; li = ji[e]; }
    }
    if (lane < NC) { sm->cval[wave * NC + lane] = cv_; sm->cidx[wave * NC + lane] = ci_; }
    __syncthreads();

    // rank-based merge 4*NC -> NC on wave 0
    if (wave == 0) {
        float mv = (lane < 4 * NC) ? sm->cval[lane] : -INFINITY;
        int   mi = (lane < 4 * NC) ? sm->cidx[lane] : 0x7fffffff;
        int rank = 0;
#pragma unroll 1
        for (int j = 0; j < 4 * NC; ++j) {
            float vj = __shfl(mv, j);
            int   ij = __shfl(mi, j);
            rank += (vj > mv || (vj == mv && ij < mi)) ? 1 : 0;
        }
        if (lane < 4 * NC && rank < NC) sm->sel[rank] = mi;
    }
    __syncthreads();

    // prefetch first 8 candidate V rows (touch every 64B line)
    float pfv[8];
#pragma unroll
    for (int c = 0; c < 8; ++c)
        pfv[c] = Vf[(size_t)sm->sel[c] * D + tid * 4];

    // rerank: wave w handles candidates w, w+4; waves 0,1 also 8,9
    {
        const float* k0r = Kf + (size_t)sm->sel[wave] * D;
        const float* k1r = Kf + (size_t)sm->sel[wave + 4] * D;
        const float* k2r = Kf + (size_t)sm->sel[8 + (wave & 1)] * D;
        double a0 = 0.0, a1 = 0.0, a2 = 0.0;
#pragma unroll 4
        for (int j = 0; j < 8; ++j) {
            const int e = lane * 2 + j * 128;
            const float2 q2 = *(const float2*)&sm->qrow[e];
            const float2 kA = *(const float2*)&k0r[e];
            const float2 kB = *(const float2*)&k1r[e];
            const float2 kC = *(const float2*)&k2r[e];
            a0 = fma((double)q2.x, (double)kA.x, fma((double)q2.y, (double)kA.y, a0));
            a1 = fma((double)q2.x, (double)kB.x, fma((double)q2.y, (double)kB.y, a1));
            a2 = fma((double)q2.x, (double)kC.x, fma((double)q2.y, (double)kC.y, a2));
        }
#pragma unroll
        for (int off = 32; off > 0; off >>= 1) {
            a0 += __shfl_xor(a0, off);
            a1 += __shfl_xor(a1, off);
            a2 += __shfl_xor(a2, off);
        }
        if (lane == 0) {
            sm->cscore[wave]     = a0;
            sm->cscore[wave + 4] = a1;
            if (wave < 2) sm->cscore[8 + wave] = a2;
        }
    }

    // consume prefetch values (keeps loads live; no output effect)
    {
        float pf = 0.f;
#pragma unroll
        for (int c = 0; c < 8; ++c) pf += pfv[c];
        asm volatile("" :: "v"(pf));
    }
    __syncthreads();

    // lane-parallel top-8 of NC + softmax on wave 0
    if (wave == 0) {
        double sc_ = (lane < NC) ? sm->cscore[lane] : -1.0e308;
        int    id_ = (lane < NC) ? sm->sel[lane]    : 0x7fffffff;
        int rank = 0;
#pragma unroll
        for (int j = 0; j < NC; ++j) {
            double vj = __shfl(sc_, j);
            int    ij = __shfl(id_, j);
            rank += (vj > sc_ || (vj == sc_ && ij < id_)) ? 1 : 0;
        }
        double mm = sc_;
#pragma unroll
        for (int off = 32; off > 0; off >>= 1) mm = fmax(mm, __shfl_xor(mm, off));
        double e = (rank < 8 && lane < NC) ? exp((sc_ - mm) / TEMP) : 0.0;
        double sum = e;
#pragma unroll
        for (int off = 32; off > 0; off >>= 1) sum += __shfl_xor(sum, off);
        if (rank < 8 && lane < NC) {
            float wk = (float)(e / sum);
            sm->wts[rank] = wk; sm->topi_s[rank] = id_;
            const size_t row = (size_t)batch * P + p;
            routes_out[row * 8 + rank]  = (float)id_;
            weights_out[row * 8 + rank] = wk;
        }
    }
    __syncthreads();

    // V gather + weighted sum (rows mostly L2-hot from prefetch)
    float4 a = {0.f, 0.f, 0.f, 0.f};
#pragma unroll
    for (int k = 0; k < 8; ++k) {
        const float4 v4 = ((const float4*)(Vf + (size_t)sm->topi_s[k] * D))[tid];
        float wk = sm->wts[k];
        a.x = fmaf(wk, v4.x, a.x);
        a.y = fmaf(wk, v4.y, a.y);
        a.z = fmaf(wk, v4.z, a.z);
        a.w = fmaf(wk, v4.w, a.w);
    }
    ((float4*)(feat_out + ((size_t)batch * P + p) * D))[tid] = a;
}

// ================= kernels =================

// fused QKV: even blockIdx.x -> i8 Q+K projection tile; odd -> bf16 V tile
__global__ __launch_bounds__(256, 2) void gemm_qkv(
    const signed char* __restrict__ Xl,
    const signed char* __restrict__ Wql,
    const signed char* __restrict__ Wkl,
    const double* __restrict__ xsc,
    const double* __restrict__ wqsc, const double* __restrict__ wksc,
    const float* __restrict__ bq, const float* __restrict__ bk,
    float* __restrict__ Qf, float* __restrict__ Kf,
    const short* __restrict__ xh, const short* __restrict__ Wvh,
    const float* __restrict__ bv, float* __restrict__ Vf)
{
    __shared__ __align__(16) signed char iA[4 * 64 * 64];
    __shared__ __align__(16) signed char iBq[4 * 64 * 64];
    __shared__ __align__(16) signed char iBk[4 * 64 * 64];
    __shared__ __align__(16) char vA[64 * 64];
    __shared__ __align__(16) char vB[64 * 64];
    const int xt = blockIdx.x >> 1, yt = blockIdx.y, tid = threadIdx.x;
    if (blockIdx.x & 1)
        v64_body(vA, vB, xt, yt, tid, xh, Wvh, bv, Vf);
    else
        i8qk_body(iA, iBq, iBk, xt, yt, tid, Xl, Wql, Wkl,
                  xsc, wqsc, wksc, bq, bk, Qf, Kf);
}

// standalone prep_x (first batch)
__global__ __launch_bounds__(256) void prep_x(
    const float* __restrict__ src, signed char* __restrict__ limbs,
    long plane_stride, double* __restrict__ scale,
    short* __restrict__ hi)
{
    __shared__ PrepSm psm;
    prepx_body(&psm, blockIdx.x, threadIdx.x, src, limbs, plane_stride, scale, hi);
}

// fused: even blockIdx.x -> topk for batch b; odd -> prep_x for batch b+1
__global__ __launch_bounds__(256) void topk_prepx(
    const float* __restrict__ S,
    const float* __restrict__ Qf,
    const float* __restrict__ Kf,
    const float* __restrict__ Vf,
    float* __restrict__ routes_out,
    float* __restrict__ weights_out,
    float* __restrict__ feat_out,
    int batch,
    const float* __restrict__ xnext, signed char* __restrict__ Xl,
    long plane_stride, double* __restrict__ xsc, short* __restrict__ xh)
{
    __shared__ TopkSm tsm;
    __shared__ PrepSm psm;
    const int tid = threadIdx.x;
    if (blockIdx.x & 1)
        prepx_body(&psm, blockIdx.x >> 1, tid, xnext, Xl, plane_stride, xsc, xh);
    else
        topk_body(&tsm, blockIdx.x >> 1, tid, S, Qf, Kf, Vf,
                  routes_out, weights_out, feat_out, batch);
}

// standalone topk (last batch)
__global__ __launch_bounds__(256) void topk_route(
    const float* __restrict__ S,
    const float* __restrict__ Qf,
    const float* __restrict__ Kf,
    const float* __restrict__ Vf,
    float* __restrict__ routes_out,
    float* __restrict__ weights_out,
    float* __restrict__ feat_out,
    int batch)
{
    __shared__ TopkSm tsm;
    topk_body(&tsm, blockIdx.x, threadIdx.x, S, Qf, Kf, Vf,
              routes_out, weights_out, feat_out, batch);
}

// ------- score GEMM: 64x64 tile, FP16 inputs (noise ~2e-5), fp32 out -------
__global__ __launch_bounds__(256, 4) void gemm_score(
    const short* __restrict__ Qh, const short* __restrict__ Kh,
    float* __restrict__ C)
{
    const int K = 1024, N = 2048;
    __shared__ __align__(16) short As[64][32];
    __shared__ __align__(16) short Bs[64][32];
    const int tid = threadIdx.x, lane = tid & 63, wave = tid >> 6;
    const int wm = wave >> 1, wn = wave & 1;
    const int quad = lane >> 4, l16 = lane & 15;
    const int m0 = blockIdx.y * 64, n0 = blockIdx.x * 64;
    const int srow = tid >> 2;
    const int cswz = ((tid & 3) ^ ((srow >> 1) & 3));
    const char* ap = (const char*)(Qh + (size_t)(m0 + srow) * K) + cswz * 16;
    const char* bp = (const char*)(Kh + (size_t)(n0 + srow) * K) + cswz * 16;
    char* aw = (char*)As + (wave << 10);
    char* bw = (char*)Bs + (wave << 10);

    f4 acc[2][2] = {};
    for (int k0 = 0; k0 < K; k0 += 32) {
        __syncthreads();
        g2l16(ap + 2 * k0, aw);
        g2l16(bp + 2 * k0, bw);
        __syncthreads();

        h8v af[2], bf[2];
#pragma unroll
        for (int t = 0; t < 2; ++t) {
            const int Ra = wm * 32 + t * 16 + l16;
            const int Rb = wn * 32 + t * 16 + l16;
            af[t] = *(const h8v*)((const char*)As + Ra * 64 + ((quad ^ ((Ra >> 1) & 3)) << 4));
            bf[t] = *(const h8v*)((const char*)Bs + Rb * 64 + ((quad ^ ((Rb >> 1) & 3)) << 4));
        }
#pragma unroll
        for (int mt = 0; mt < 2; ++mt)
#pragma unroll
            for (int nt = 0; nt < 2; ++nt)
                acc[mt][nt] = __builtin_amdgcn_mfma_f32_16x16x32_f16(
                    af[mt], bf[nt], acc[mt][nt], 0, 0, 0);
    }
#pragma unroll
    for (int mt = 0; mt < 2; ++mt)
#pragma unroll
        for (int nt = 0; nt < 2; ++nt)
#pragma unroll
            for (int r = 0; r < 4; ++r) {
                int row = m0 + wm * 32 + mt * 16 + quad * 4 + r;
                int col = n0 + wn * 32 + nt * 16 + l16;
                C[(size_t)row * N + col] = acc[mt][nt][r];
            }
}

// ------- fp32 in-place L2 normalize (fp64 norm accumulation) + FP16 copy -------
__global__ __launch_bounds__(256) void l2norm_f32h16(
    float* __restrict__ fq, float* __restrict__ fk,
    short* __restrict__ hq, short* __restrict__ hk)
{
    float* f = blockIdx.y ? fk : fq;
    short* h = blockIdx.y ? hk : hq;
    const int row = blockIdx.x;
    const int tid = threadIdx.x;
    float4* p4 = (float4*)(f + (size_t)row * 1024);
    float4 v = p4[tid];
    double s = (double)v.x * v.x + (double)v.y * v.y
             + (double)v.z * v.z + (double)v.w * v.w;
#pragma unroll
    for (int off = 32; off > 0; off >>= 1) s += __shfl_down(s, off);
    __shared__ double ws[5];
    if ((tid & 63) == 0) ws[tid >> 6] = s;
    __syncthreads();
    if (tid == 0) ws[4] = fmax(sqrt(ws[0] + ws[1] + ws[2] + ws[3]), 1e-12);
    __syncthreads();
    const double inv = 1.0 / ws[4];
    float o0 = (float)(v.x * inv), o1 = (float)(v.y * inv);
    float o2 = (float)(v.z * inv), o3 = (float)(v.w * inv);
    float4 o = make_float4(o0, o1, o2, o3);
    p4[tid] = o;
    __align__(8) _Float16 hv[4] = {(_Float16)o0, (_Float16)o1,
                                   (_Float16)o2, (_Float16)o3};
    *(short4*)&h[(size_t)row * 1024 + tid * 4] = *(short4*)hv;
}

extern "C" void kernel_launch(void* const* d_in, const int* in_sizes, int n_in,
                              void* d_out, int out_size, void* d_ws, size_t ws_size,
                              hipStream_t stream)
{
    const float* x  = (const float*)d_in[0];  // (4,2049,1024)
    const float* Wq = (const float*)d_in[1];
    const float* bq = (const float*)d_in[2];
    const float* Wk = (const float*)d_in[3];
    const float* bk = (const float*)d_in[4];
    const float* Wv = (const float*)d_in[5];
    const float* bv = (const float*)d_in[6];

    const int B = 4, P = 2048, D = 1024;
    const size_t PD = (size_t)P * D;
    const size_t DD = (size_t)D * D;

    float*  Qf   = (float*)d_ws;              // P*D fp32 (projection, then normalized)
    float*  Kf   = Qf + PD;                   // P*D fp32
    double* xsc  = (double*)(Kf + PD);        // 2048
    double* wqsc = xsc + 2048;                // 1024
    double* wksc = wqsc + 1024;               // 1024
    short*  Qh   = (short*)(wksc + 1024);     // P*D fp16
    short*  Kh   = Qh + PD;
    short*  xh   = Kh + PD;                   // x bf16
    short*  Wvh  = xh + PD;                   // Wv bf16
    float*  Vf   = (float*)(Wvh + DD);        // P*D f32
    float*  Sf   = Vf + PD;                   // P*P f32
    signed char* Xl  = (signed char*)(Sf + (size_t)P * P);  // 4*P*D
    signed char* Wql = Xl + 4 * PD;                          // 4*D*D
    signed char* Wkl = Wql + 4 * DD;

    float* out     = (float*)d_out;
    float* routes  = out;
    float* weights = out + (size_t)B * P * 8;
    float* feat    = out + (size_t)B * P * 16;

    dim3 blk(256);
    prep_w<<<dim3(1024, 3), blk, 0, stream>>>(Wq, Wk, Wv, Wql, Wkl, wqsc, wksc, Wvh);
    prep_x<<<dim3(P), blk, 0, stream>>>(x + D, Xl, (long)PD, xsc, xh);  // batch 0 rows 1..2048

    for (int b = 0; b < B; ++b) {
        gemm_qkv<<<dim3(32, 32), blk, 0, stream>>>(Xl, Wql, Wkl, xsc, wqsc, wksc,
                                                   bq, bk, Qf, Kf, xh, Wvh, bv, Vf);
        l2norm_f32h16<<<dim3(P, 2), blk, 0, stream>>>(Qf, Kf, Qh, Kh);
        gemm_score<<<dim3(32, 32), blk, 0, stream>>>(Qh, Kh, Sf);
        if (b < B - 1) {
            const float* xn = x + ((size_t)(b + 1) * 2049 + 1) * D;
            topk_prepx<<<dim3(2 * P), blk, 0, stream>>>(Sf, Qf, Kf, Vf,
                                                        routes, weights, feat, b,
                                                        xn, Xl, (long)PD, xsc, xh);
        } else {
            topk_route<<<dim3(P), blk, 0, stream>>>(Sf, Qf, Kf, Vf,
                                                    routes, weights, feat, b);
        }
    }
}

// Round 14
// 595.310 us; speedup vs baseline: 1.1871x; 1.1871x over previous
//
#include <hip/hip_runtime.h>
#include <hip/hip_bf16.h>
#include <math.h>

#define TEMP 0.1
#define NC 10   // rerank candidates (true top-8 ⊂ fp16-score top-10; R9 margin model)

typedef float f4 __attribute__((ext_vector_type(4)));
typedef short s8v __attribute__((ext_vector_type(8)));
typedef int   i4v __attribute__((ext_vector_type(4)));
typedef _Float16 h8v __attribute__((ext_vector_type(8)));

__device__ inline short f2bf(float f) {
    __hip_bfloat16 h = __float2bfloat16(f);
    return *reinterpret_cast<short*>(&h);
}

// 16B global->LDS DMA: per-lane global addr, wave-uniform LDS base (+lane*16 by HW).
__device__ __forceinline__ void g2l16(const void* g, void* l) {
    __builtin_amdgcn_global_load_lds(
        (const __attribute__((address_space(1))) void*)g,
        (__attribute__((address_space(3))) void*)l, 16, 0, 0);
}

// ---------- W setup, fused: y=0 quant Wq, y=1 quant Wk, y=2 bf16-cast Wv ----------
__global__ __launch_bounds__(256) void prep_w(
    const float* __restrict__ Wq, const float* __restrict__ Wk,
    const float* __restrict__ Wv,
    signed char* __restrict__ Wql, signed char* __restrict__ Wkl,
    double* __restrict__ wqsc, double* __restrict__ wksc,
    short* __restrict__ Wvh)
{
    const int row = blockIdx.x, tid = threadIdx.x;
    const int which = blockIdx.y;
    if (which == 2) {
        const float4 v = ((const float4*)(Wv + (size_t)row * 1024))[tid];
        __align__(8) short h[4] = {f2bf(v.x), f2bf(v.y), f2bf(v.z), f2bf(v.w)};
        *(short4*)&Wvh[(size_t)row * 1024 + tid * 4] = *(short4*)h;
        return;
    }
    const float* src = which ? Wk : Wq;
    signed char* limbs = which ? Wkl : Wql;
    double* scale = which ? wksc : wqsc;
    const long plane_stride = 1024L * 1024;

    const float4 v = ((const float4*)(src + (size_t)row * 1024))[tid];
    float m = fmaxf(fmaxf(fabsf(v.x), fabsf(v.y)), fmaxf(fabsf(v.z), fabsf(v.w)));
#pragma unroll
    for (int off = 32; off > 0; off >>= 1) m = fmaxf(m, __shfl_down(m, off));
    __shared__ float wmax[4];
    __shared__ int ssig;
    if ((tid & 63) == 0) wmax[tid >> 6] = m;
    __syncthreads();
    if (tid == 0) {
        float rm = fmaxf(fmaxf(wmax[0], wmax[1]), fmaxf(wmax[2], wmax[3]));
        int sig = (rm > 0.f) ? (29 - ilogbf(rm)) : 0;
        ssig = sig;
        scale[row] = ldexp(1.0, -sig);
    }
    __syncthreads();
    const double s2 = ldexp(1.0, ssig);
    float xs[4] = {v.x, v.y, v.z, v.w};
    signed char out[4][4];
#pragma unroll
    for (int e = 0; e < 4; ++e) {
        long X = __double2ll_rn((double)xs[e] * s2);
#pragma unroll
        for (int l = 0; l < 3; ++l) {
            int d = (int)(((X + 128) & 255) - 128);
            out[l][e] = (signed char)d;
            X = (X - d) >> 8;
        }
        out[3][e] = (signed char)X;
    }
#pragma unroll
    for (int l = 0; l < 4; ++l)
        *(char4*)&limbs[(size_t)l * plane_stride + (size_t)row * 1024 + tid * 4] =
            *(char4*)&out[l][0];
}

// ---------- fused x prep: int8 limb quantize + bf16 cast (single read of x) ----------
__global__ __launch_bounds__(256) void prep_x(
    const float* __restrict__ src, signed char* __restrict__ limbs,
    long plane_stride, double* __restrict__ scale,
    short* __restrict__ hi)
{
    const int row = blockIdx.x, tid = threadIdx.x;
    const float4 v = ((const float4*)(src + (size_t)row * 1024))[tid];
    float m = fmaxf(fmaxf(fabsf(v.x), fabsf(v.y)), fmaxf(fabsf(v.z), fabsf(v.w)));
#pragma unroll
    for (int off = 32; off > 0; off >>= 1) m = fmaxf(m, __shfl_down(m, off));
    __shared__ float wmax[4];
    __shared__ int ssig;
    if ((tid & 63) == 0) wmax[tid >> 6] = m;
    __syncthreads();
    if (tid == 0) {
        float rm = fmaxf(fmaxf(wmax[0], wmax[1]), fmaxf(wmax[2], wmax[3]));
        int sig = (rm > 0.f) ? (29 - ilogbf(rm)) : 0;
        ssig = sig;
        scale[row] = ldexp(1.0, -sig);
    }
    __syncthreads();
    const double s2 = ldexp(1.0, ssig);
    float xs[4] = {v.x, v.y, v.z, v.w};
    signed char out[4][4];
    __align__(8) short h[4];
#pragma unroll
    for (int e = 0; e < 4; ++e) {
        long X = __double2ll_rn((double)xs[e] * s2);
#pragma unroll
        for (int lmb = 0; lmb < 3; ++lmb) {
            int d = (int)(((X + 128) & 255) - 128);
            out[lmb][e] = (signed char)d;
            X = (X - d) >> 8;
        }
        out[3][e] = (signed char)X;
        h[e] = f2bf(xs[e]);
    }
#pragma unroll
    for (int lmb = 0; lmb < 4; ++lmb)
        *(char4*)&limbs[(size_t)lmb * plane_stride + (size_t)row * 1024 + tid * 4] =
            *(char4*)&out[lmb][0];
    *(short4*)&hi[(size_t)row * 1024 + tid * 4] = *(short4*)h;
}

// ---------- i8-MFMA projection, Q AND K fused (shared A staging/reads) ----------
// 10 pairs (i+j>=3) x2 outputs; gload_lds staging; LDS dest linear, global source
// pre-swizzled (R6/R8-verified involution). A-tile staged once, read once, used
// for both Wq and Wk MFMAs.
__global__ __launch_bounds__(256, 2) void gemm_i8qk(
    const signed char* __restrict__ Xl,
    const signed char* __restrict__ Wql,
    const signed char* __restrict__ Wkl,
    const double* __restrict__ xsc,
    const double* __restrict__ wqsc, const double* __restrict__ wksc,
    const float* __restrict__ bq, const float* __restrict__ bk,
    float* __restrict__ Qf, float* __restrict__ Kf)
{
    const int K = 1024, N = 1024;
    const long MK = 2048L * 1024, NK = 1024L * 1024;

    __shared__ __align__(16) signed char Asm[4][64][64];
    __shared__ __align__(16) signed char Bqm[4][64][64];
    __shared__ __align__(16) signed char Bkm[4][64][64];

    const int tid  = threadIdx.x;
    const int lane = tid & 63, wave = tid >> 6;
    const int wm = wave >> 1, wn = wave & 1;
    const int quad = lane >> 4, l16 = lane & 15;
    const int m0 = blockIdx.y * 64, n0 = blockIdx.x * 64;

    const int srow = tid >> 2;
    const int cswz = ((tid & 3) ^ ((srow >> 1) & 3));
    const signed char* ap  = Xl  + (size_t)(m0 + srow) * K + cswz * 16;
    const signed char* bqp = Wql + (size_t)(n0 + srow) * K + cswz * 16;
    const signed char* bkp = Wkl + (size_t)(n0 + srow) * K + cswz * 16;

    signed char* aw  = (signed char*)Asm + (wave << 10);
    signed char* bqw = (signed char*)Bqm + (wave << 10);
    signed char* bkw = (signed char*)Bkm + (wave << 10);

    i4v accq[4][2][2] = {};   // level s = i+j-3
    i4v acck[4][2][2] = {};

    const int R0  = wm * 32 + l16;
    const int R1  = wm * 32 + 16 + l16;
    const int c0  = (quad ^ ((R0 >> 1) & 3)) * 16;
    const int c1  = (quad ^ ((R1 >> 1) & 3)) * 16;
    const int Rn0 = wn * 32 + l16;
    const int Rn1 = wn * 32 + 16 + l16;
    const int cn0 = (quad ^ ((Rn0 >> 1) & 3)) * 16;
    const int cn1 = (quad ^ ((Rn1 >> 1) & 3)) * 16;

    for (int k0 = 0; k0 < K; k0 += 64) {
        __syncthreads();
#pragma unroll
        for (int l = 0; l < 4; ++l) {
            g2l16(ap  + l * MK + k0, aw  + l * 4096);
            g2l16(bqp + l * NK + k0, bqw + l * 4096);
            g2l16(bkp + l * NK + k0, bkw + l * 4096);
        }
        __syncthreads();

        // A fragments for all limbs (read once, feed both Q and K MFMAs)
        i4v aF0[4], aF1[4];
#pragma unroll
        for (int i = 0; i < 4; ++i) {
            aF0[i] = *(const i4v*)&Asm[i][R0][c0];
            aF1[i] = *(const i4v*)&Asm[i][R1][c1];
        }

#pragma unroll
        for (int j = 0; j < 4; ++j) {
            i4v bq0 = *(const i4v*)&Bqm[j][Rn0][cn0];
            i4v bq1 = *(const i4v*)&Bqm[j][Rn1][cn1];
            i4v bk0 = *(const i4v*)&Bkm[j][Rn0][cn0];
            i4v bk1 = *(const i4v*)&Bkm[j][Rn1][cn1];
#pragma unroll
            for (int i = 0; i < 4; ++i) {
                if (i + j < 3) continue;
                const int s = i + j - 3;
                accq[s][0][0] = __builtin_amdgcn_mfma_i32_16x16x64_i8(aF0[i], bq0, accq[s][0][0], 0, 0, 0);
                accq[s][0][1] = __builtin_amdgcn_mfma_i32_16x16x64_i8(aF0[i], bq1, accq[s][0][1], 0, 0, 0);
                accq[s][1][0] = __builtin_amdgcn_mfma_i32_16x16x64_i8(aF1[i], bq0, accq[s][1][0], 0, 0, 0);
                accq[s][1][1] = __builtin_amdgcn_mfma_i32_16x16x64_i8(aF1[i], bq1, accq[s][1][1], 0, 0, 0);
                acck[s][0][0] = __builtin_amdgcn_mfma_i32_16x16x64_i8(aF0[i], bk0, acck[s][0][0], 0, 0, 0);
                acck[s][0][1] = __builtin_amdgcn_mfma_i32_16x16x64_i8(aF0[i], bk1, acck[s][0][1], 0, 0, 0);
                acck[s][1][0] = __builtin_amdgcn_mfma_i32_16x16x64_i8(aF1[i], bk0, acck[s][1][0], 0, 0, 0);
                acck[s][1][1] = __builtin_amdgcn_mfma_i32_16x16x64_i8(aF1[i], bk1, acck[s][1][1], 0, 0, 0);
            }
        }
    }

    const double wt0 = ldexp(1.0, 24), wt1 = ldexp(1.0, 32);
    const double wt2 = ldexp(1.0, 40), wt3 = ldexp(1.0, 48);
#pragma unroll
    for (int mt = 0; mt < 2; ++mt)
#pragma unroll
        for (int nt = 0; nt < 2; ++nt)
#pragma unroll
            for (int r = 0; r < 4; ++r) {
                int row = m0 + wm * 32 + mt * 16 + quad * 4 + r;
                int col = n0 + wn * 32 + nt * 16 + l16;
                const double xr = xsc[row];
                double dq = wt0 * (double)accq[0][mt][nt][r]
                          + wt1 * (double)accq[1][mt][nt][r]
                          + wt2 * (double)accq[2][mt][nt][r]
                          + wt3 * (double)accq[3][mt][nt][r];
                Qf[(size_t)row * N + col] =
                    (float)(dq * xr * wqsc[col] + (double)bq[col]);
                double dk = wt0 * (double)acck[0][mt][nt][r]
                          + wt1 * (double)acck[1][mt][nt][r]
                          + wt2 * (double)acck[2][mt][nt][r]
                          + wt3 * (double)acck[3][mt][nt][r];
                Kf[(size_t)row * N + col] =
                    (float)(dk * xr * wksc[col] + (double)bk[col]);
            }
}

// ------- V projection, pure bf16 single-MFMA; gload_lds staging + swizzle -------
__global__ __launch_bounds__(256, 4) void gemm_v64(
    const short* __restrict__ Ahp, const short* __restrict__ Bhp,
    const float* __restrict__ bias, float* __restrict__ C)
{
    const int K = 1024, N = 1024;
    __shared__ __align__(16) short Ah[64][32];
    __shared__ __align__(16) short Bh[64][32];

    const int tid = threadIdx.x, lane = tid & 63, wave = tid >> 6;
    const int wm = wave >> 1, wn = wave & 1;
    const int quad = lane >> 4, l16 = lane & 15;
    const int m0 = blockIdx.y * 64, n0 = blockIdx.x * 64;
    const int srow = tid >> 2;
    const int cswz = ((tid & 3) ^ ((srow >> 1) & 3));
    const char* ap = (const char*)(Ahp + (size_t)(m0 + srow) * K) + cswz * 16;
    const char* bp = (const char*)(Bhp + (size_t)(n0 + srow) * K) + cswz * 16;
    char* aw = (char*)Ah + (wave << 10);
    char* bw = (char*)Bh + (wave << 10);

    f4 acc[2][2] = {};
    for (int k0 = 0; k0 < K; k0 += 32) {
        __syncthreads();
        g2l16(ap + 2 * k0, aw);
        g2l16(bp + 2 * k0, bw);
        __syncthreads();

        s8v af[2], bf[2];
#pragma unroll
        for (int t = 0; t < 2; ++t) {
            const int Ra = wm * 32 + t * 16 + l16;
            const int Rb = wn * 32 + t * 16 + l16;
            af[t] = *(const s8v*)((const char*)Ah + Ra * 64 + ((quad ^ ((Ra >> 1) & 3)) << 4));
            bf[t] = *(const s8v*)((const char*)Bh + Rb * 64 + ((quad ^ ((Rb >> 1) & 3)) << 4));
        }
#pragma unroll
        for (int mt = 0; mt < 2; ++mt)
#pragma unroll
            for (int nt = 0; nt < 2; ++nt)
                acc[mt][nt] = __builtin_amdgcn_mfma_f32_16x16x32_bf16(
                    af[mt], bf[nt], acc[mt][nt], 0, 0, 0);
    }
#pragma unroll
    for (int mt = 0; mt < 2; ++mt)
#pragma unroll
        for (int nt = 0; nt < 2; ++nt)
#pragma unroll
            for (int r = 0; r < 4; ++r) {
                int row = m0 + wm * 32 + mt * 16 + quad * 4 + r;
                int col = n0 + wn * 32 + nt * 16 + l16;
                C[(size_t)row * N + col] = acc[mt][nt][r] + bias[col];
            }
}

// ------- score GEMM: 64x64 tile, FP16 inputs (noise ~2e-5), fp32 out -------
__global__ __launch_bounds__(256, 4) void gemm_score(
    const short* __restrict__ Qh, const short* __restrict__ Kh,
    float* __restrict__ C)
{
    const int K = 1024, N = 2048;
    __shared__ __align__(16) short As[64][32];
    __shared__ __align__(16) short Bs[64][32];
    const int tid = threadIdx.x, lane = tid & 63, wave = tid >> 6;
    const int wm = wave >> 1, wn = wave & 1;
    const int quad = lane >> 4, l16 = lane & 15;
    const int m0 = blockIdx.y * 64, n0 = blockIdx.x * 64;
    const int srow = tid >> 2;
    const int cswz = ((tid & 3) ^ ((srow >> 1) & 3));
    const char* ap = (const char*)(Qh + (size_t)(m0 + srow) * K) + cswz * 16;
    const char* bp = (const char*)(Kh + (size_t)(n0 + srow) * K) + cswz * 16;
    char* aw = (char*)As + (wave << 10);
    char* bw = (char*)Bs + (wave << 10);

    f4 acc[2][2] = {};
    for (int k0 = 0; k0 < K; k0 += 32) {
        __syncthreads();
        g2l16(ap + 2 * k0, aw);
        g2l16(bp + 2 * k0, bw);
        __syncthreads();

        h8v af[2], bf[2];
#pragma unroll
        for (int t = 0; t < 2; ++t) {
            const int Ra = wm * 32 + t * 16 + l16;
            const int Rb = wn * 32 + t * 16 + l16;
            af[t] = *(const h8v*)((const char*)As + Ra * 64 + ((quad ^ ((Ra >> 1) & 3)) << 4));
            bf[t] = *(const h8v*)((const char*)Bs + Rb * 64 + ((quad ^ ((Rb >> 1) & 3)) << 4));
        }
#pragma unroll
        for (int mt = 0; mt < 2; ++mt)
#pragma unroll
            for (int nt = 0; nt < 2; ++nt)
                acc[mt][nt] = __builtin_amdgcn_mfma_f32_16x16x32_f16(
                    af[mt], bf[nt], acc[mt][nt], 0, 0, 0);
    }
#pragma unroll
    for (int mt = 0; mt < 2; ++mt)
#pragma unroll
        for (int nt = 0; nt < 2; ++nt)
#pragma unroll
            for (int r = 0; r < 4; ++r) {
                int row = m0 + wm * 32 + mt * 16 + quad * 4 + r;
                int col = n0 + wn * 32 + nt * 16 + l16;
                C[(size_t)row * N + col] = acc[mt][nt][r];
            }
}

// ------- fp32 in-place L2 normalize (fp64 norm accumulation) + FP16 copy -------
__global__ __launch_bounds__(256) void l2norm_f32h16(
    float* __restrict__ fq, float* __restrict__ fk,
    short* __restrict__ hq, short* __restrict__ hk)
{
    float* f = blockIdx.y ? fk : fq;
    short* h = blockIdx.y ? hk : hq;
    const int row = blockIdx.x;
    const int tid = threadIdx.x;
    float4* p4 = (float4*)(f + (size_t)row * 1024);
    float4 v = p4[tid];
    double s = (double)v.x * v.x + (double)v.y * v.y
             + (double)v.z * v.z + (double)v.w * v.w;
#pragma unroll
    for (int off = 32; off > 0; off >>= 1) s += __shfl_down(s, off);
    __shared__ double ws[5];
    if ((tid & 63) == 0) ws[tid >> 6] = s;
    __syncthreads();
    if (tid == 0) ws[4] = fmax(sqrt(ws[0] + ws[1] + ws[2] + ws[3]), 1e-12);
    __syncthreads();
    const double inv = 1.0 / ws[4];
    float o0 = (float)(v.x * inv), o1 = (float)(v.y * inv);
    float o2 = (float)(v.z * inv), o3 = (float)(v.w * inv);
    float4 o = make_float4(o0, o1, o2, o3);
    p4[tid] = o;
    __align__(8) _Float16 hv[4] = {(_Float16)o0, (_Float16)o1,
                                   (_Float16)o2, (_Float16)o3};
    *(short4*)&h[(size_t)row * 1024 + tid * 4] = *(short4*)hv;
}

// ------- top-NC selection (register tournament) + fp32-input/fp64-accum rerank
//         + 8-row V prefetch + lane-parallel softmax -------
__global__ __launch_bounds__(256) void topk_route(
    const float*  __restrict__ S,
    const float*  __restrict__ Qf,
    const float*  __restrict__ Kf,
    const float*  __restrict__ Vf,
    float* __restrict__ routes_out,
    float* __restrict__ weights_out,
    float* __restrict__ feat_out,
    int batch)
{
    const int P = 2048, D = 1024;
    __shared__ float  qrow[1024];
    __shared__ float  cval[4 * NC];
    __shared__ int    cidx[4 * NC];
    __shared__ int    sel[NC];
    __shared__ double cscore[NC];
    __shared__ int    topi_s[8];
    __shared__ float  wts[8];

    const int p = blockIdx.x;
    const int tid = threadIdx.x;
    const int lane = tid & 63, wave = tid >> 6;

    const float4* sr4 = (const float4*)(S + (size_t)p * P);
    const float4 s0 = sr4[tid];
    const float4 s1 = sr4[tid + 256];
    ((float4*)qrow)[tid] = ((const float4*)(Qf + (size_t)p * D))[tid];

    float v[8] = {s0.x, s0.y, s0.z, s0.w, s1.x, s1.y, s1.z, s1.w};
    int   ji[8];
#pragma unroll
    for (int e = 0; e < 8; ++e) {
        ji[e] = (e < 4) ? (4 * tid + e) : (1024 + 4 * tid + (e - 4));
        if (ji[e] == p) v[e] = -1e30f;   // diagonal mask
    }

    float lv = v[0]; int li = ji[0];
#pragma unroll
    for (int e = 1; e < 8; ++e)
        if (v[e] > lv) { lv = v[e]; li = ji[e]; }

    // ---- per-wave top-NC register tournament (no barriers) ----
    float cv_ = -INFINITY; int ci_ = 0x7fffffff;
#pragma unroll 1
    for (int it = 0; it < NC; ++it) {
        float bv = lv; int bi = li;
#pragma unroll
        for (int off = 32; off > 0; off >>= 1) {
            float ov = __shfl_xor(bv, off);
            int   oi = __shfl_xor(bi, off);
            if (ov > bv || (ov == bv && oi < bi)) { bv = ov; bi = oi; }
        }
        if (lane == it) { cv_ = bv; ci_ = bi; }
#pragma unroll
        for (int e = 0; e < 8; ++e)
            if (ji[e] == bi) v[e] = -INFINITY;
        lv = v[0]; li = ji[0];
#pragma unroll
        for (int e = 1; e < 8; ++e)
            if (v[e] > lv) { lv = v[e]; li = ji[e]; }
    }
    if (lane < NC) { cval[wave * NC + lane] = cv_; cidx[wave * NC + lane] = ci_; }
    __syncthreads();

    // ---- rank-based merge 4*NC -> NC on wave 0 ----
    if (wave == 0) {
        float mv = (lane < 4 * NC) ? cval[lane] : -INFINITY;
        int   mi = (lane < 4 * NC) ? cidx[lane] : 0x7fffffff;
        int rank = 0;
#pragma unroll 1
        for (int j = 0; j < 4 * NC; ++j) {
            float vj = __shfl(mv, j);
            int   ij = __shfl(mi, j);
            rank += (vj > mv || (vj == mv && ij < mi)) ? 1 : 0;
        }
        if (lane < 4 * NC && rank < NC) sel[rank] = mi;
    }
    __syncthreads();

    // ---- prefetch first 8 candidate V rows (covers final set ~94% of rows) ----
    float pfv[8];
#pragma unroll
    for (int c = 0; c < 8; ++c)
        pfv[c] = Vf[(size_t)sel[c] * D + tid * 4];

    // ---- rerank: wave w handles candidates w, w+4; waves 0,1 also 8,9 ----
    {
        const float* k0r = Kf + (size_t)sel[wave] * D;
        const float* k1r = Kf + (size_t)sel[wave + 4] * D;
        const float* k2r = Kf + (size_t)sel[8 + (wave & 1)] * D;
        double a0 = 0.0, a1 = 0.0, a2 = 0.0;
#pragma unroll 4
        for (int j = 0; j < 8; ++j) {
            const int e = lane * 2 + j * 128;
            const float2 q2 = *(const float2*)&qrow[e];
            const float2 kA = *(const float2*)&k0r[e];
            const float2 kB = *(const float2*)&k1r[e];
            const float2 kC = *(const float2*)&k2r[e];
            a0 = fma((double)q2.x, (double)kA.x, fma((double)q2.y, (double)kA.y, a0));
            a1 = fma((double)q2.x, (double)kB.x, fma((double)q2.y, (double)kB.y, a1));
            a2 = fma((double)q2.x, (double)kC.x, fma((double)q2.y, (double)kC.y, a2));
        }
#pragma unroll
        for (int off = 32; off > 0; off >>= 1) {
            a0 += __shfl_xor(a0, off);
            a1 += __shfl_xor(a1, off);
            a2 += __shfl_xor(a2, off);
        }
        if (lane == 0) {
            cscore[wave]     = a0;
            cscore[wave + 4] = a1;
            if (wave < 2) cscore[8 + wave] = a2;
        }
    }

    // consume prefetch values (keeps loads live; no output effect)
    {
        float pf = 0.f;
#pragma unroll
        for (int c = 0; c < 8; ++c) pf += pfv[c];
        asm volatile("" :: "v"(pf));
    }
    __syncthreads();

    // ---- lane-parallel top-8 of NC + softmax on wave 0 ----
    if (wave == 0) {
        double sc_ = (lane < NC) ? cscore[lane] : -1.0e308;
        int    id_ = (lane < NC) ? sel[lane]    : 0x7fffffff;
        int rank = 0;
#pragma unroll
        for (int j = 0; j < NC; ++j) {
            double vj = __shfl(sc_, j);
            int    ij = __shfl(id_, j);
            rank += (vj > sc_ || (vj == sc_ && ij < id_)) ? 1 : 0;
        }
        double mm = sc_;
#pragma unroll
        for (int off = 32; off > 0; off >>= 1) mm = fmax(mm, __shfl_xor(mm, off));
        double e = (rank < 8 && lane < NC) ? exp((sc_ - mm) / TEMP) : 0.0;
        double sum = e;
#pragma unroll
        for (int off = 32; off > 0; off >>= 1) sum += __shfl_xor(sum, off);
        if (rank < 8 && lane < NC) {
            float wk = (float)(e / sum);
            wts[rank] = wk; topi_s[rank] = id_;
            const size_t row = (size_t)batch * P + p;
            routes_out[row * 8 + rank]  = (float)id_;
            weights_out[row * 8 + rank] = wk;
        }
    }
    __syncthreads();

    // ---- V gather + weighted sum (rows mostly L2-hot from prefetch) ----
    float4 a = {0.f, 0.f, 0.f, 0.f};
#pragma unroll
    for (int k = 0; k < 8; ++k) {
        const float4 v4 = ((const float4*)(Vf + (size_t)topi_s[k] * D))[tid];
        float wk = wts[k];
        a.x = fmaf(wk, v4.x, a.x);
        a.y = fmaf(wk, v4.y, a.y);
        a.z = fmaf(wk, v4.z, a.z);
        a.w = fmaf(wk, v4.w, a.w);
    }
    ((float4*)(feat_out + ((size_t)batch * P + p) * D))[tid] = a;
}

extern "C" void kernel_launch(void* const* d_in, const int* in_sizes, int n_in,
                              void* d_out, int out_size, void* d_ws, size_t ws_size,
                              hipStream_t stream)
{
    const float* x  = (const float*)d_in[0];  // (4,2049,1024)
    const float* Wq = (const float*)d_in[1];
    const float* bq = (const float*)d_in[2];
    const float* Wk = (const float*)d_in[3];
    const float* bk = (const float*)d_in[4];
    const float* Wv = (const float*)d_in[5];
    const float* bv = (const float*)d_in[6];

    const int B = 4, P = 2048, D = 1024;
    const size_t PD = (size_t)P * D;
    const size_t DD = (size_t)D * D;

    float*  Qf   = (float*)d_ws;              // P*D fp32 (projection, then normalized)
    float*  Kf   = Qf + PD;                   // P*D fp32
    double* xsc  = (double*)(Kf + PD);        // 2048
    double* wqsc = xsc + 2048;                // 1024
    double* wksc = wqsc + 1024;               // 1024
    short*  Qh   = (short*)(wksc + 1024);     // P*D fp16
    short*  Kh   = Qh + PD;
    short*  xh   = Kh + PD;                   // x bf16
    short*  Wvh  = xh + PD;                   // Wv bf16
    float*  Vf   = (float*)(Wvh + DD);        // P*D f32
    float*  Sf   = Vf + PD;                   // P*P f32
    signed char* Xl  = (signed char*)(Sf + (size_t)P * P);  // 4*P*D
    signed char* Wql = Xl + 4 * PD;                          // 4*D*D
    signed char* Wkl = Wql + 4 * DD;

    float* out     = (float*)d_out;
    float* routes  = out;
    float* weights = out + (size_t)B * P * 8;
    float* feat    = out + (size_t)B * P * 16;

    dim3 blk(256);
    prep_w<<<dim3(1024, 3), blk, 0, stream>>>(Wq, Wk, Wv, Wql, Wkl, wqsc, wksc, Wvh);

    for (int b = 0; b < B; ++b) {
        const float* xb = x + ((size_t)b * 2049 + 1) * D;  // rows 1..2048 contiguous
        prep_x<<<dim3(P), blk, 0, stream>>>(xb, Xl, (long)PD, xsc, xh);
        gemm_i8qk<<<dim3(16, 32), blk, 0, stream>>>(Xl, Wql, Wkl, xsc, wqsc, wksc,
                                                    bq, bk, Qf, Kf);
        gemm_v64<<<dim3(16, 32), blk, 0, stream>>>(xh, Wvh, bv, Vf);
        l2norm_f32h16<<<dim3(P, 2), blk, 0, stream>>>(Qf, Kf, Qh, Kh);
        gemm_score<<<dim3(32, 32), blk, 0, stream>>>(Qh, Kh, Sf);
        topk_route<<<dim3(P), blk, 0, stream>>>(Sf, Qf, Kf, Vf, routes, weights, feat, b);
    }
}